// Round 3
// baseline (238.106 us; speedup 1.0000x reference)
//
#include <hip/hip_runtime.h>
#include <math.h>

#define HF  14
#define DIM 16384
#define NTH 1024
#define PRE_STRIDE 384

// ---- precompute per step n: ry[k=1..9][q]=(cos(th/2),sin(th/2)), alpha[k=1..8][q]=omega_k+phi_{k+1}
__global__ void k_pre(const float* __restrict__ w1, float* __restrict__ pre)
{
    int tid = threadIdx.x;
    if (tid < 252) {
        int n = tid / 126, r = tid % 126, k0 = r / 14, q = r % 14;  // k0 = layer-1
        float th = w1[n*378 + k0*42 + q*3 + 1];
        float s, c; sincosf(0.5f * th, &s, &c);
        pre[n*PRE_STRIDE + (k0*14 + q)*2 + 0] = c;
        pre[n*PRE_STRIDE + (k0*14 + q)*2 + 1] = s;
    } else if (tid >= 256 && tid < 480) {
        int idx = tid - 256, n = idx / 112, r = idx % 112, k0 = r / 14, q = r % 14;
        pre[n*PRE_STRIDE + 252 + k0*14 + q] =
            w1[n*378 + k0*42 + q*3 + 2] + w1[n*378 + (k0+1)*42 + q*3 + 0];
    }
}

// ---- linear_down
__global__ void k_down(const float* __restrict__ x, const float* __restrict__ wd,
                       const float* __restrict__ bd, float* __restrict__ xr)
{
    int row  = blockIdx.x;
    int wave = threadIdx.x >> 6;
    int lane = threadIdx.x & 63;
    const float* xrow = x + row * 784;
    for (int f = wave; f < HF; f += 4) {
        const float* wrow = wd + f * 784;
        float s = 0.f;
        for (int j = lane; j < 784; j += 64) s = fmaf(xrow[j], wrow[j], s);
        #pragma unroll
        for (int off = 32; off; off >>= 1) s += __shfl_xor(s, off);
        if (lane == 0) xr[row * HF + f] = s + bd[f];
    }
}

// ---- BatchNorm1d (batch stats over 64 rows)
__global__ void k_bn(const float* __restrict__ xr, const float* __restrict__ bw,
                     const float* __restrict__ bb, float* __restrict__ out)
{
    int t = threadIdx.x;
    for (int f = 0; f < HF; ++f) {
        float v = xr[t * HF + f];
        float s = v;
        #pragma unroll
        for (int off = 32; off; off >>= 1) s += __shfl_xor(s, off);
        float mu = s * (1.f / 64.f);
        float dv = v - mu;
        float q = dv * dv;
        #pragma unroll
        for (int off = 32; off; off >>= 1) q += __shfl_xor(q, off);
        float var = q * (1.f / 64.f);
        out[t * HF + f] = dv * (1.f / sqrtf(var + 1e-5f)) * bw[f] + bb[f];
    }
}

// ---- statevector circuit: 1024 thr, 16 amps/thread, barrier-free lane swaps
__global__ __launch_bounds__(NTH)
void k_circuit(const float* __restrict__ xrin, const float* __restrict__ pre,
               float* __restrict__ xrout)
{
    __shared__ float2 S[DIM];        // 128 KB staging (reused for final reduce)
    __shared__ float2 ryt[126];      // (c,s), layer-major
    __shared__ float  alp[112];      // alpha_k[q]
    __shared__ float  alpx[28];      // alpha + x for k=3,6
    int row = blockIdx.x, T = threadIdx.x, L = T & 63, wv = T >> 6;

    if (T < 126) ryt[T] = ((const float2*)pre)[T];
    else if (T >= 128 && T < 240) alp[T - 128] = pre[252 + (T - 128)];
    __syncthreads();
    if (T < 28) {
        int q = T % 14, which = T / 14;       // 0 -> k=3, 1 -> k=6
        alpx[T] = alp[(which ? 5 : 2) * 14 + q] + xrin[row * HF + q];
    }
    __syncthreads();

    // slot -> wire bookkeeping (uniform)
    int QR[4] = {0, 1, 2, 3};
    int QL[6] = {4, 5, 6, 7, 8, 9};
    int QW[4] = {10, 11, 12, 13};

    float2 v[16];

    // init: product state after RY layer 1
    {
        float pt = 1.f;
        #pragma unroll
        for (int j = 0; j < 6; ++j) { float2 cs = ryt[4 + j]; pt *= ((T >> j) & 1) ? cs.y : cs.x; }
        #pragma unroll
        for (int j = 0; j < 4; ++j) { float2 cs = ryt[10 + j]; pt *= ((T >> (6 + j)) & 1) ? cs.y : cs.x; }
        float c0 = ryt[0].x, s0 = ryt[0].y, c1 = ryt[1].x, s1 = ryt[1].y;
        float c2 = ryt[2].x, s2 = ryt[2].y, c3 = ryt[3].x, s3 = ryt[3].y;
        #pragma unroll
        for (int r = 0; r < 16; ++r) {
            float p = pt;
            p *= (r & 1) ? s0 : c0;  p *= (r & 2) ? s1 : c1;
            p *= (r & 4) ? s2 : c2;  p *= (r & 8) ? s3 : c3;
            v[r] = make_float2(p, 0.f);
        }
    }

    auto diag = [&](int k) {   // apply Delta_k pointwise
        const float* ab = (k == 3) ? alpx : (k == 6) ? alpx + 14 : alp + (k - 1) * 14;
        int czr = ((k - 1) % 3) + 1;
        int Wt = 0; float at = 0.f;
        #pragma unroll
        for (int j = 0; j < 6; ++j) {
            int b = (T >> j) & 1;
            if (b) { Wt |= 1 << QL[j]; at += ab[QL[j]]; }
        }
        #pragma unroll
        for (int j = 0; j < 4; ++j) {
            int b = (T >> (6 + j)) & 1;
            if (b) { Wt |= 1 << QW[j]; at += ab[QW[j]]; }
        }
        int m0 = 1 << QR[0], m1 = 1 << QR[1], m2 = 1 << QR[2], m3 = 1 << QR[3];
        float a0 = ab[QR[0]], a1 = ab[QR[1]], a2 = ab[QR[2]], a3 = ab[QR[3]];
        #pragma unroll
        for (int r = 0; r < 16; ++r) {
            int W = Wt; float ang = at;
            if (r & 1) { W |= m0; ang += a0; }
            if (r & 2) { W |= m1; ang += a1; }
            if (r & 4) { W |= m2; ang += a2; }
            if (r & 8) { W |= m3; ang += a3; }
            int rot = ((W >> czr) | (W << (14 - czr))) & 16383;
            if (__popc(W & rot) & 1) ang += 3.14159265358979323f;
            float sn, cs; __sincosf(ang, &sn, &cs);
            float nr = v[r].x * cs - v[r].y * sn;
            float ni = v[r].x * sn + v[r].y * cs;
            v[r].x = nr; v[r].y = ni;
        }
    };
    diag(1);

    auto gates = [&](int k, int nq) {  // RY_k on element bits 0..nq-1 (wires QR[j])
        #pragma unroll
        for (int j = 0; j < 4; ++j) {
            if (j >= nq) continue;
            float2 cs = ryt[(k - 1) * 14 + QR[j]];
            float c = cs.x, s = cs.y;
            #pragma unroll
            for (int m = 0; m < 8; ++m) {
                int r0 = ((m >> j) << (j + 1)) | (m & ((1 << j) - 1));
                int r1 = r0 | (1 << j);
                float a0r = v[r0].x, a0i = v[r0].y, a1r = v[r1].x, a1i = v[r1].y;
                v[r0].x = c * a0r - s * a1r;  v[r0].y = c * a0i - s * a1i;
                v[r1].x = s * a0r + c * a1r;  v[r1].y = s * a0i + c * a1i;
            }
        }
    };

    int mbase = wv << 10;                 // per-wave 1024-float2 region

    #pragma unroll 1
    for (int k = 2; k <= 9; ++k) {
        gates(k, 4);                                        // pass A

        {   // miniT1: swap element bits 0-3 <-> lane bits 0-3 (within-wave, no barrier)
            int wb = mbase | L;
            #pragma unroll
            for (int r = 0; r < 16; ++r) S[wb ^ (r * 65)] = v[r];
            int rb = mbase | ((L & 15) << 6) | L;
            #pragma unroll
            for (int r = 0; r < 16; ++r) v[r] = S[rb ^ r];
            int t;
            t = QR[0]; QR[0] = QL[0]; QL[0] = t;
            t = QR[1]; QR[1] = QL[1]; QL[1] = t;
            t = QR[2]; QR[2] = QL[2]; QL[2] = t;
            t = QR[3]; QR[3] = QL[3]; QL[3] = t;
        }
        gates(k, 4);                                        // pass B

        {   // miniT2: swap element bits 0-1 <-> lane bits 4-5 (within-wave)
            int wb = mbase | L;
            #pragma unroll
            for (int r = 0; r < 16; ++r) S[wb ^ (r * 65)] = v[r];
            int rb2 = mbase | ((L >> 4) << 6) | ((L & 15) ^ (L >> 4));
            #pragma unroll
            for (int r = 0; r < 16; ++r)
                v[r] = S[rb2 ^ (((r & 12) << 6) | ((r & 3) << 4) | (r & 12))];
            int t;
            t = QR[0]; QR[0] = QL[4]; QL[4] = t;
            t = QR[1]; QR[1] = QL[5]; QL[5] = t;
        }
        gates(k, 2);                                        // pass C

        {   // fullT: swap element bits 0-3 <-> wave bits 0-3 (2 barriers)
            int fw = (T << 4) | (T & 15);
            #pragma unroll
            for (int r = 0; r < 16; ++r) S[fw ^ r] = v[r];
            __syncthreads();
            int fr = (L << 4) | (wv ^ (L & 15));
            #pragma unroll
            for (int r = 0; r < 16; ++r) v[r] = S[fr + (r << 10)];
            __syncthreads();
            int t;
            t = QR[0]; QR[0] = QW[0]; QW[0] = t;
            t = QR[1]; QR[1] = QW[1]; QW[1] = t;
            t = QR[2]; QR[2] = QW[2]; QW[2] = t;
            t = QR[3]; QR[3] = QW[3]; QW[3] = t;
        }
        gates(k, 4);                                        // pass D

        if (k < 9) diag(k);
    }
    // trailing diagonal (CZ + omega_9) dropped: probs invariant.

    // measurement: <Z_q> = sum_w (tot_w - 2 * M[w][q])
    float ptot = 0.f, Sr0 = 0.f, Sr1 = 0.f, Sr2 = 0.f, Sr3 = 0.f;
    #pragma unroll
    for (int r = 0; r < 16; ++r) {
        float p = fmaf(v[r].x, v[r].x, v[r].y * v[r].y);
        ptot += p;
        if (r & 1) Sr0 += p;
        if (r & 2) Sr1 += p;
        if (r & 4) Sr2 += p;
        if (r & 8) Sr3 += p;
    }
    float Sl[6];
    #pragma unroll
    for (int j = 0; j < 6; ++j) Sl[j] = ((T >> j) & 1) ? ptot : 0.f;
    float tot = ptot;
    #pragma unroll
    for (int off = 32; off; off >>= 1) {
        tot += __shfl_xor(tot, off);
        Sr0 += __shfl_xor(Sr0, off);
        Sr1 += __shfl_xor(Sr1, off);
        Sr2 += __shfl_xor(Sr2, off);
        Sr3 += __shfl_xor(Sr3, off);
        #pragma unroll
        for (int j = 0; j < 6; ++j) Sl[j] += __shfl_xor(Sl[j], off);
    }
    float* M = (float*)S;    // M[w][16]: [0..13] per-wire one-sums, [14] = tot
    if ((T & 63) == 0) {
        int b = wv * 16;
        M[b + QR[0]] = Sr0; M[b + QR[1]] = Sr1; M[b + QR[2]] = Sr2; M[b + QR[3]] = Sr3;
        #pragma unroll
        for (int j = 0; j < 6; ++j) M[b + QL[j]] = Sl[j];
        #pragma unroll
        for (int j = 0; j < 4; ++j) M[b + QW[j]] = ((wv >> j) & 1) ? tot : 0.f;
        M[b + 14] = tot;
    }
    __syncthreads();
    if (T < HF) {
        float o = 0.f;
        #pragma unroll
        for (int w = 0; w < 16; ++w) o += M[w * 16 + 14] - 2.f * M[w * 16 + T];
        xrout[row * HF + T] = o;
    }
}

// ---- linear_up
__global__ void k_up(const float* __restrict__ xr, const float* __restrict__ wu,
                     const float* __restrict__ bu, float* __restrict__ out)
{
    int b = blockIdx.x;
    float xvv[HF];
    #pragma unroll
    for (int f = 0; f < HF; ++f) xvv[f] = xr[b * HF + f];
    for (int j = threadIdx.x; j < 784; j += 256) {
        float s = bu[j];
        #pragma unroll
        for (int f = 0; f < HF; ++f) s = fmaf(xvv[f], wu[j * HF + f], s);
        out[b * 784 + j] = s;
    }
}

extern "C" void kernel_launch(void* const* d_in, const int* in_sizes, int n_in,
                              void* d_out, int out_size, void* d_ws, size_t ws_size,
                              hipStream_t stream)
{
    const float* x  = (const float*)d_in[0];
    const float* wd = (const float*)d_in[1];
    const float* bd = (const float*)d_in[2];
    const float* bw = (const float*)d_in[3];
    const float* bb = (const float*)d_in[4];
    const float* w1 = (const float*)d_in[5];
    const float* wu = (const float*)d_in[6];
    const float* bu = (const float*)d_in[7];
    float* out = (float*)d_out;

    float* ws   = (float*)d_ws;
    float* pre  = ws;           // 2 * 384 floats
    float* xr   = ws + 1024;    // 64*14
    float* xrbn = ws + 2048;    // 64*14

    hipLaunchKernelGGL(k_pre,  dim3(1),  dim3(512), 0, stream, w1, pre);
    hipLaunchKernelGGL(k_down, dim3(64), dim3(256), 0, stream, x, wd, bd, xr);
    for (int n = 0; n < 2; ++n) {
        hipLaunchKernelGGL(k_bn,      dim3(1),  dim3(64),  0, stream, xr, bw, bb, xrbn);
        hipLaunchKernelGGL(k_circuit, dim3(64), dim3(NTH), 0, stream, xrbn,
                           pre + n * PRE_STRIDE, xr);
    }
    hipLaunchKernelGGL(k_up, dim3(64), dim3(256), 0, stream, xr, wu, bu, out);
}

// Round 4
// 164.504 us; speedup vs baseline: 1.4474x; 1.4474x over previous
//
#include <hip/hip_runtime.h>
#include <math.h>

#define HF  14
#define DIM 16384
#define NTH 1024
#define PRE_STRIDE 384
#define INV2PI 0.15915494309189535f

typedef float v2f __attribute__((ext_vector_type(2)));
static __device__ __forceinline__ v2f sp(float x) { return (v2f){x, x}; }

// ---- precompute per step n: ry[k=1..9][q]=(cos(th/2),sin(th/2)),
// ----                        alpha[k=1..8][q]=(omega_k+phi_{k+1})/(2*pi)  [revolutions]
__global__ void k_pre(const float* __restrict__ w1, float* __restrict__ pre)
{
    int tid = threadIdx.x;
    if (tid < 252) {
        int n = tid / 126, r = tid % 126, k0 = r / 14, q = r % 14;  // k0 = layer-1
        float th = w1[n*378 + k0*42 + q*3 + 1];
        float s, c; sincosf(0.5f * th, &s, &c);
        pre[n*PRE_STRIDE + (k0*14 + q)*2 + 0] = c;
        pre[n*PRE_STRIDE + (k0*14 + q)*2 + 1] = s;
    } else if (tid >= 256 && tid < 480) {
        int idx = tid - 256, n = idx / 112, r = idx % 112, k0 = r / 14, q = r % 14;
        pre[n*PRE_STRIDE + 252 + k0*14 + q] =
            (w1[n*378 + k0*42 + q*3 + 2] + w1[n*378 + (k0+1)*42 + q*3 + 0]) * INV2PI;
    }
}

// ---- linear_down
__global__ void k_down(const float* __restrict__ x, const float* __restrict__ wd,
                       const float* __restrict__ bd, float* __restrict__ xr)
{
    int row  = blockIdx.x;
    int wave = threadIdx.x >> 6;
    int lane = threadIdx.x & 63;
    const float* xrow = x + row * 784;
    for (int f = wave; f < HF; f += 4) {
        const float* wrow = wd + f * 784;
        float s = 0.f;
        for (int j = lane; j < 784; j += 64) s = fmaf(xrow[j], wrow[j], s);
        #pragma unroll
        for (int off = 32; off; off >>= 1) s += __shfl_xor(s, off);
        if (lane == 0) xr[row * HF + f] = s + bd[f];
    }
}

// ---- BatchNorm1d (batch stats over 64 rows)
__global__ void k_bn(const float* __restrict__ xr, const float* __restrict__ bw,
                     const float* __restrict__ bb, float* __restrict__ out)
{
    int t = threadIdx.x;
    for (int f = 0; f < HF; ++f) {
        float v = xr[t * HF + f];
        float s = v;
        #pragma unroll
        for (int off = 32; off; off >>= 1) s += __shfl_xor(s, off);
        float mu = s * (1.f / 64.f);
        float dv = v - mu;
        float q = dv * dv;
        #pragma unroll
        for (int off = 32; off; off >>= 1) q += __shfl_xor(q, off);
        float var = q * (1.f / 64.f);
        out[t * HF + f] = dv * (1.f / sqrtf(var + 1e-5f)) * bw[f] + bb[f];
    }
}

// ---- statevector circuit: 1024 thr, 16 amps/thread, packed f32 math ------
__global__ __launch_bounds__(NTH)
void k_circuit(const float* __restrict__ xrin, const float* __restrict__ pre,
               float* __restrict__ xrout)
{
    __shared__ v2f   S[DIM];        // 128 KB staging (reused for final reduce)
    __shared__ float2 ryt[126];     // (c,s), layer-major
    __shared__ float  alp[112];     // alpha_k[q] in revolutions
    __shared__ float  alpx[28];     // alpha + x/(2pi) for k=3,6
    int row = blockIdx.x, T = threadIdx.x, L = T & 63, wv = T >> 6;

    if (T < 126) ryt[T] = ((const float2*)pre)[T];
    else if (T >= 128 && T < 240) alp[T - 128] = pre[252 + (T - 128)];
    __syncthreads();
    if (T < 28) {
        int q = T % 14, which = T / 14;       // 0 -> k=3, 1 -> k=6
        alpx[T] = alp[(which ? 5 : 2) * 14 + q] + xrin[row * HF + q] * INV2PI;
    }
    __syncthreads();

    // slot -> wire bookkeeping (uniform)
    int QR[4] = {0, 1, 2, 3};
    int QL[6] = {4, 5, 6, 7, 8, 9};
    int QW[4] = {10, 11, 12, 13};

    v2f v[16];

    // init: product state after RY layer 1
    {
        float pt = 1.f;
        #pragma unroll
        for (int j = 0; j < 6; ++j) { float2 cs = ryt[4 + j]; pt *= ((T >> j) & 1) ? cs.y : cs.x; }
        #pragma unroll
        for (int j = 0; j < 4; ++j) { float2 cs = ryt[10 + j]; pt *= ((T >> (6 + j)) & 1) ? cs.y : cs.x; }
        float c0 = ryt[0].x, s0 = ryt[0].y, c1 = ryt[1].x, s1 = ryt[1].y;
        float c2 = ryt[2].x, s2 = ryt[2].y, c3 = ryt[3].x, s3 = ryt[3].y;
        #pragma unroll
        for (int r = 0; r < 16; ++r) {
            float p = pt;
            p *= (r & 1) ? s0 : c0;  p *= (r & 2) ? s1 : c1;
            p *= (r & 4) ? s2 : c2;  p *= (r & 8) ? s3 : c3;
            v[r] = (v2f){p, 0.f};
        }
    }

    auto diag = [&](int k) {   // apply Delta_k pointwise (angles in revolutions)
        const float* ab = (k == 3) ? alpx : (k == 6) ? alpx + 14 : alp + (k - 1) * 14;
        int czr = ((k - 1) % 3) + 1;
        int Wt = 0; float at = 0.f;
        #pragma unroll
        for (int j = 0; j < 6; ++j) {
            int b = (T >> j) & 1;
            if (b) { Wt |= 1 << QL[j]; at += ab[QL[j]]; }
        }
        #pragma unroll
        for (int j = 0; j < 4; ++j) {
            int b = (T >> (6 + j)) & 1;
            if (b) { Wt |= 1 << QW[j]; at += ab[QW[j]]; }
        }
        int m0 = 1 << QR[0], m1 = 1 << QR[1], m2 = 1 << QR[2], m3 = 1 << QR[3];
        float a0 = ab[QR[0]], a1 = ab[QR[1]], a2 = ab[QR[2]], a3 = ab[QR[3]];
        #pragma unroll
        for (int r = 0; r < 16; ++r) {
            int W = Wt; float ang = at;
            if (r & 1) { W |= m0; ang += a0; }
            if (r & 2) { W |= m1; ang += a1; }
            if (r & 4) { W |= m2; ang += a2; }
            if (r & 8) { W |= m3; ang += a3; }
            int rot = ((W >> czr) | (W << (14 - czr))) & 16383;
            if (__popc(W & rot) & 1) ang += 0.5f;
            float t  = __builtin_amdgcn_fractf(ang);
            float sn = __builtin_amdgcn_sinf(t);
            float cs = __builtin_amdgcn_cosf(t);
            v2f z = v[r];
            v2f u = (v2f){-z.y, z.x};
            v[r] = sp(cs) * z + sp(sn) * u;
        }
    };
    diag(1);

    auto gates = [&](int k, int nq) {  // RY_k on element bits 0..nq-1 (wires QR[j])
        #pragma unroll
        for (int j = 0; j < 4; ++j) {
            if (j >= nq) continue;
            float2 cs2 = ryt[(k - 1) * 14 + QR[j]];
            float c = cs2.x, s = cs2.y;
            #pragma unroll
            for (int m = 0; m < 8; ++m) {
                int r0 = ((m >> j) << (j + 1)) | (m & ((1 << j) - 1));
                int r1 = r0 | (1 << j);
                v2f a0 = v[r0], a1 = v[r1];
                v[r0] = sp(c) * a0 - sp(s) * a1;
                v[r1] = sp(s) * a0 + sp(c) * a1;
            }
        }
    };

    int mbase = wv << 10;                 // per-wave 1024-v2f region

    #pragma unroll 1
    for (int k = 2; k <= 9; ++k) {
        gates(k, 4);                                        // pass A

        {   // miniT1: swap element bits 0-3 <-> lane bits 0-3 (within-wave, no barrier)
            int wb = mbase | L;
            #pragma unroll
            for (int r = 0; r < 16; ++r) S[wb ^ (r * 65)] = v[r];
            int rb = mbase | ((L & 15) << 6) | L;
            #pragma unroll
            for (int r = 0; r < 16; ++r) v[r] = S[rb ^ r];
            int t;
            t = QR[0]; QR[0] = QL[0]; QL[0] = t;
            t = QR[1]; QR[1] = QL[1]; QL[1] = t;
            t = QR[2]; QR[2] = QL[2]; QL[2] = t;
            t = QR[3]; QR[3] = QL[3]; QL[3] = t;
        }
        gates(k, 4);                                        // pass B

        {   // miniT2: swap element bits 0-1 <-> lane bits 4-5 (within-wave)
            int wb = mbase | L;
            #pragma unroll
            for (int r = 0; r < 16; ++r) S[wb ^ (r * 65)] = v[r];
            int rb2 = mbase | ((L >> 4) << 6) | ((L & 15) ^ (L >> 4));
            #pragma unroll
            for (int r = 0; r < 16; ++r)
                v[r] = S[rb2 ^ (((r & 12) << 6) | ((r & 3) << 4) | (r & 12))];
            int t;
            t = QR[0]; QR[0] = QL[4]; QL[4] = t;
            t = QR[1]; QR[1] = QL[5]; QL[5] = t;
        }
        gates(k, 2);                                        // pass C

        {   // fullT: swap element bits 0-3 <-> wave bits 0-3 (2 barriers)
            int fw = (T << 4) | (T & 15);
            #pragma unroll
            for (int r = 0; r < 16; ++r) S[fw ^ r] = v[r];
            __syncthreads();
            int fr = (L << 4) | (wv ^ (L & 15));
            #pragma unroll
            for (int r = 0; r < 16; ++r) v[r] = S[fr + (r << 10)];
            __syncthreads();
            int t;
            t = QR[0]; QR[0] = QW[0]; QW[0] = t;
            t = QR[1]; QR[1] = QW[1]; QW[1] = t;
            t = QR[2]; QR[2] = QW[2]; QW[2] = t;
            t = QR[3]; QR[3] = QW[3]; QW[3] = t;
        }
        gates(k, 4);                                        // pass D

        if (k < 9) diag(k);
    }
    // trailing diagonal (CZ + omega_9) dropped: probs invariant.

    // measurement: <Z_q> = sum_w (tot_w - 2 * M[w][q])
    float ptot = 0.f, Sr0 = 0.f, Sr1 = 0.f, Sr2 = 0.f, Sr3 = 0.f;
    #pragma unroll
    for (int r = 0; r < 16; ++r) {
        float p = fmaf(v[r].x, v[r].x, v[r].y * v[r].y);
        ptot += p;
        if (r & 1) Sr0 += p;
        if (r & 2) Sr1 += p;
        if (r & 4) Sr2 += p;
        if (r & 8) Sr3 += p;
    }
    float Sl[6];
    #pragma unroll
    for (int j = 0; j < 6; ++j) Sl[j] = ((T >> j) & 1) ? ptot : 0.f;
    float tot = ptot;
    #pragma unroll
    for (int off = 32; off; off >>= 1) {
        tot += __shfl_xor(tot, off);
        Sr0 += __shfl_xor(Sr0, off);
        Sr1 += __shfl_xor(Sr1, off);
        Sr2 += __shfl_xor(Sr2, off);
        Sr3 += __shfl_xor(Sr3, off);
        #pragma unroll
        for (int j = 0; j < 6; ++j) Sl[j] += __shfl_xor(Sl[j], off);
    }
    float* M = (float*)S;    // M[w][16]: [0..13] per-wire one-sums, [14] = tot
    if ((T & 63) == 0) {
        int b = wv * 16;
        M[b + QR[0]] = Sr0; M[b + QR[1]] = Sr1; M[b + QR[2]] = Sr2; M[b + QR[3]] = Sr3;
        #pragma unroll
        for (int j = 0; j < 6; ++j) M[b + QL[j]] = Sl[j];
        #pragma unroll
        for (int j = 0; j < 4; ++j) M[b + QW[j]] = ((wv >> j) & 1) ? tot : 0.f;
        M[b + 14] = tot;
    }
    __syncthreads();
    if (T < HF) {
        float o = 0.f;
        #pragma unroll
        for (int w = 0; w < 16; ++w) o += M[w * 16 + 14] - 2.f * M[w * 16 + T];
        xrout[row * HF + T] = o;
    }
}

// ---- linear_up
__global__ void k_up(const float* __restrict__ xr, const float* __restrict__ wu,
                     const float* __restrict__ bu, float* __restrict__ out)
{
    int b = blockIdx.x;
    float xvv[HF];
    #pragma unroll
    for (int f = 0; f < HF; ++f) xvv[f] = xr[b * HF + f];
    for (int j = threadIdx.x; j < 784; j += 256) {
        float s = bu[j];
        #pragma unroll
        for (int f = 0; f < HF; ++f) s = fmaf(xvv[f], wu[j * HF + f], s);
        out[b * 784 + j] = s;
    }
}

extern "C" void kernel_launch(void* const* d_in, const int* in_sizes, int n_in,
                              void* d_out, int out_size, void* d_ws, size_t ws_size,
                              hipStream_t stream)
{
    const float* x  = (const float*)d_in[0];
    const float* wd = (const float*)d_in[1];
    const float* bd = (const float*)d_in[2];
    const float* bw = (const float*)d_in[3];
    const float* bb = (const float*)d_in[4];
    const float* w1 = (const float*)d_in[5];
    const float* wu = (const float*)d_in[6];
    const float* bu = (const float*)d_in[7];
    float* out = (float*)d_out;

    float* ws   = (float*)d_ws;
    float* pre  = ws;           // 2 * 384 floats
    float* xr   = ws + 1024;    // 64*14
    float* xrbn = ws + 2048;    // 64*14

    hipLaunchKernelGGL(k_pre,  dim3(1),  dim3(512), 0, stream, w1, pre);
    hipLaunchKernelGGL(k_down, dim3(64), dim3(256), 0, stream, x, wd, bd, xr);
    for (int n = 0; n < 2; ++n) {
        hipLaunchKernelGGL(k_bn,      dim3(1),  dim3(64),  0, stream, xr, bw, bb, xrbn);
        hipLaunchKernelGGL(k_circuit, dim3(64), dim3(NTH), 0, stream, xrbn,
                           pre + n * PRE_STRIDE, xr);
    }
    hipLaunchKernelGGL(k_up, dim3(64), dim3(256), 0, stream, xr, wu, bu, out);
}